// Round 1
// baseline (4604.177 us; speedup 1.0000x reference)
//
#include <hip/hip_runtime.h>
#include <math.h>

#define B_ROWS 32768
#define D_DIM  512
#define K_EMB  8192

#define BM 64
#define BN 128
#define BK 32

// ---------------------------------------------------------------------------
// Row squared-norm: one 64-lane wave per row (D=512 -> 8 floats/lane).
// ---------------------------------------------------------------------------
__global__ __launch_bounds__(256) void rownorm_kernel(
    const float* __restrict__ X, float* __restrict__ out, int nrows) {
  const int wave = threadIdx.x >> 6;
  const int lane = threadIdx.x & 63;
  const int row = blockIdx.x * 4 + wave;
  if (row >= nrows) return;
  const float* xr = X + (size_t)row * D_DIM;
  float4 a = *(const float4*)(xr + lane * 4);
  float4 b = *(const float4*)(xr + 256 + lane * 4);
  float s = a.x * a.x + a.y * a.y + a.z * a.z + a.w * a.w +
            b.x * b.x + b.y * b.y + b.z * b.z + b.w * b.w;
  #pragma unroll
  for (int o = 32; o > 0; o >>= 1) s += __shfl_xor(s, o, 64);
  if (lane == 0) out[row] = s;
}

// ---------------------------------------------------------------------------
// Fused distance-GEMM + running argmin.
// Block tile: BM=64 z-rows x BN=128 codes, K(D)-staged through LDS in BK=32.
// 256 threads as 16x16: thread (tx,ty) computes 4 rows x 8 cols.
// Distance d = (zz[r] + wsq[k]) - 2*dot  (matches reference expression order).
// ---------------------------------------------------------------------------
__global__ __launch_bounds__(256) void argmin_kernel(
    const float* __restrict__ z, const float* __restrict__ W,
    const float* __restrict__ zz, const float* __restrict__ wsq,
    int* __restrict__ out_idx, float* __restrict__ out_idx_f,
    int* __restrict__ hist) {
  __shared__ float As[BK][BM];    // 8 KB, stored transposed: As[d][m]
  __shared__ float Bs[BK][BN];    // 16 KB, Bs[d][n]
  __shared__ float redv[BM][16];  // 4 KB
  __shared__ int   redi[BM][16];  // 4 KB

  const int tid = threadIdx.x;
  const int tx = tid & 15;   // col group: cols tx*8 .. tx*8+7
  const int ty = tid >> 4;   // row group: rows ty*4 .. ty*4+3
  const int row0 = blockIdx.x * BM;

  // A staging: thread -> row tid/4 (0..63), cols (tid%4)*8 + {0..7}  (2 float4)
  const int la_r = tid >> 2;
  const int la_c = (tid & 3) * 8;
  // B staging: thread -> row tid/2 (0..127), cols (tid%2)*16 + {0..15} (4 float4)
  const int lb_r = tid >> 1;
  const int lb_c = (tid & 1) * 16;

  float zzr[4];
  #pragma unroll
  for (int i = 0; i < 4; ++i) zzr[i] = zz[row0 + ty * 4 + i];

  float best[4];
  int   bidx[4];
  #pragma unroll
  for (int i = 0; i < 4; ++i) { best[i] = INFINITY; bidx[i] = 0x7fffffff; }

  for (int kt = 0; kt < K_EMB; kt += BN) {
    float acc[4][8];
    #pragma unroll
    for (int i = 0; i < 4; ++i)
      #pragma unroll
      for (int j = 0; j < 8; ++j) acc[i][j] = 0.f;

    for (int d0 = 0; d0 < D_DIM; d0 += BK) {
      const float* ap = z + (size_t)(row0 + la_r) * D_DIM + d0 + la_c;
      float4 a0 = *(const float4*)ap;
      float4 a1 = *(const float4*)(ap + 4);
      const float* bp = W + (size_t)(kt + lb_r) * D_DIM + d0 + lb_c;
      float4 b0 = *(const float4*)bp;
      float4 b1 = *(const float4*)(bp + 4);
      float4 b2 = *(const float4*)(bp + 8);
      float4 b3 = *(const float4*)(bp + 12);

      __syncthreads();  // previous iter's LDS reads complete before overwrite
      As[la_c + 0][la_r] = a0.x; As[la_c + 1][la_r] = a0.y;
      As[la_c + 2][la_r] = a0.z; As[la_c + 3][la_r] = a0.w;
      As[la_c + 4][la_r] = a1.x; As[la_c + 5][la_r] = a1.y;
      As[la_c + 6][la_r] = a1.z; As[la_c + 7][la_r] = a1.w;
      Bs[lb_c +  0][lb_r] = b0.x; Bs[lb_c +  1][lb_r] = b0.y;
      Bs[lb_c +  2][lb_r] = b0.z; Bs[lb_c +  3][lb_r] = b0.w;
      Bs[lb_c +  4][lb_r] = b1.x; Bs[lb_c +  5][lb_r] = b1.y;
      Bs[lb_c +  6][lb_r] = b1.z; Bs[lb_c +  7][lb_r] = b1.w;
      Bs[lb_c +  8][lb_r] = b2.x; Bs[lb_c +  9][lb_r] = b2.y;
      Bs[lb_c + 10][lb_r] = b2.z; Bs[lb_c + 11][lb_r] = b2.w;
      Bs[lb_c + 12][lb_r] = b3.x; Bs[lb_c + 13][lb_r] = b3.y;
      Bs[lb_c + 14][lb_r] = b3.z; Bs[lb_c + 15][lb_r] = b3.w;
      __syncthreads();

      #pragma unroll
      for (int d = 0; d < BK; ++d) {
        float av[4], bv[8];
        *(float4*)av       = *(const float4*)&As[d][ty * 4];
        *(float4*)bv       = *(const float4*)&Bs[d][tx * 8];
        *(float4*)(bv + 4) = *(const float4*)&Bs[d][tx * 8 + 4];
        #pragma unroll
        for (int i = 0; i < 4; ++i)
          #pragma unroll
          for (int j = 0; j < 8; ++j)
            acc[i][j] = fmaf(av[i], bv[j], acc[i][j]);
      }
    }

    // Score this k-tile, update running argmin (registers only).
    #pragma unroll
    for (int j = 0; j < 8; ++j) {
      const int col = kt + tx * 8 + j;
      const float wv = wsq[col];
      #pragma unroll
      for (int i = 0; i < 4; ++i) {
        float dist = (zzr[i] + wv) - 2.0f * acc[i][j];
        if (dist < best[i]) { best[i] = dist; bidx[i] = col; }
      }
    }
  }

  __syncthreads();
  #pragma unroll
  for (int i = 0; i < 4; ++i) {
    redv[ty * 4 + i][tx] = best[i];
    redi[ty * 4 + i][tx] = bidx[i];
  }
  __syncthreads();

  if (tid < BM) {
    float bv = INFINITY;
    int bi = 0x7fffffff;
    #pragma unroll
    for (int t = 0; t < 16; ++t) {  // ascending tx; tie -> lowest index (np.argmin)
      float v = redv[tid][t];
      int ix = redi[tid][t];
      if (v < bv || (v == bv && ix < bi)) { bv = v; bi = ix; }
    }
    const int row = row0 + tid;
    out_idx[row] = bi;
    out_idx_f[row] = (float)bi;
    atomicAdd(&hist[bi], 1);
  }
}

// ---------------------------------------------------------------------------
// Gather quantized = W[idx], write straight-through output z + (q - z),
// accumulate sum((z - q)^2) into a double accumulator.
// One wave per row.
// ---------------------------------------------------------------------------
__global__ __launch_bounds__(256) void gather_kernel(
    const float* __restrict__ z, const float* __restrict__ W,
    const int* __restrict__ idx, float* __restrict__ out,
    double* __restrict__ mse_sum) {
  const int wave = threadIdx.x >> 6;
  const int lane = threadIdx.x & 63;
  const int row = blockIdx.x * 4 + wave;
  const int k = idx[row];
  const float* zr = z + (size_t)row * D_DIM;
  const float* wr = W + (size_t)k * D_DIM;
  float* outr = out + (size_t)row * D_DIM;
  float s = 0.f;
  #pragma unroll
  for (int h = 0; h < 2; ++h) {
    const int c = h * 256 + lane * 4;
    float4 zv = *(const float4*)(zr + c);
    float4 qv = *(const float4*)(wr + c);
    float4 st;
    st.x = zv.x + (qv.x - zv.x);
    st.y = zv.y + (qv.y - zv.y);
    st.z = zv.z + (qv.z - zv.z);
    st.w = zv.w + (qv.w - zv.w);
    float dx = zv.x - qv.x, dy = zv.y - qv.y, dz = zv.z - qv.z, dw = zv.w - qv.w;
    s += dx * dx + dy * dy + dz * dz + dw * dw;
    *(float4*)(outr + c) = st;
  }
  #pragma unroll
  for (int o = 32; o > 0; o >>= 1) s += __shfl_xor(s, o, 64);
  if (lane == 0) atomicAdd(mse_sum, (double)s);
}

// ---------------------------------------------------------------------------
// Entropy over the code histogram + final loss scalar.
// ---------------------------------------------------------------------------
__global__ __launch_bounds__(256) void loss_kernel(
    const int* __restrict__ hist, const double* __restrict__ mse_sum,
    float* __restrict__ out_loss) {
  __shared__ float ls[4];
  const int tid = threadIdx.x;
  float e = 0.f;
  for (int b = tid; b < K_EMB; b += 256) {
    float p = (float)hist[b] * (1.0f / 32768.0f);
    e += p * logf(p + 1e-10f);
  }
  #pragma unroll
  for (int o = 32; o > 0; o >>= 1) e += __shfl_xor(e, o, 64);
  if ((tid & 63) == 0) ls[tid >> 6] = e;
  __syncthreads();
  if (tid == 0) {
    float entropy = -(ls[0] + ls[1] + ls[2] + ls[3]);
    float mse = (float)(*mse_sum / 16777216.0);  // mean over B*D
    float entropy_loss = 1.0f - entropy / logf(8192.0f);
    // codebook + COMMITMENT_COST*commitment + ENTROPY_WEIGHT*entropy_loss
    float loss = mse + 0.25f * mse + 0.1f * entropy_loss;
    out_loss[0] = loss;
  }
}

// ---------------------------------------------------------------------------
extern "C" void kernel_launch(void* const* d_in, const int* in_sizes, int n_in,
                              void* d_out, int out_size, void* d_ws, size_t ws_size,
                              hipStream_t stream) {
  const float* z = (const float*)d_in[0];  // [32768,512]
  const float* W = (const float*)d_in[1];  // [8192,512]
  float* out = (float*)d_out;              // [B*D] st | [1] loss | [B] indices

  char* ws = (char*)d_ws;
  double* mse_sum = (double*)ws;                          // 8 B (+8 pad)
  int*   hist = (int*)(ws + 16);                          // 8192 ints
  float* zz   = (float*)(ws + 16 + 32768);                // 32768 floats
  float* wsq  = (float*)(ws + 16 + 32768 + 131072);       // 8192 floats
  int*   idx  = (int*)(ws + 16 + 32768 + 131072 + 32768); // 32768 ints

  // zero the accumulator + histogram (ws is poisoned before every launch)
  hipMemsetAsync(d_ws, 0, 16 + 32768, stream);

  rownorm_kernel<<<B_ROWS / 4, 256, 0, stream>>>(z, zz, B_ROWS);
  rownorm_kernel<<<K_EMB / 4, 256, 0, stream>>>(W, wsq, K_EMB);

  argmin_kernel<<<B_ROWS / BM, 256, 0, stream>>>(
      z, W, zz, wsq, idx, out + (size_t)B_ROWS * D_DIM + 1, hist);

  gather_kernel<<<B_ROWS / 4, 256, 0, stream>>>(z, W, idx, out, mse_sum);

  loss_kernel<<<1, 256, 0, stream>>>(hist, mse_sum,
                                     out + (size_t)B_ROWS * D_DIM);
}

// Round 2
// 1676.604 us; speedup vs baseline: 2.7461x; 2.7461x over previous
//
#include <hip/hip_runtime.h>
#include <math.h>

#define B_ROWS 32768
#define D_DIM  512
#define K_EMB  8192

#define BMT 128          // z-rows per block tile
#define BNT 128          // codes per block tile
#define KSPLIT 2
#define KRANGE (K_EMB / KSPLIT)   // 4096 codes per block

typedef __attribute__((ext_vector_type(4))) float f32x4;
typedef __attribute__((ext_vector_type(8))) short bf16x8;  // 8 bf16 in 4 VGPRs

// async global->LDS, 16 B per lane; LDS dest is wave-uniform base + lane*16
#define GLL16(gp, lp)                                                          \
  __builtin_amdgcn_global_load_lds(                                            \
      (const __attribute__((address_space(1))) void*)(gp),                     \
      (__attribute__((address_space(3))) void*)(lp), 16, 0, 0)

// ---------------------------------------------------------------------------
// Row squared-norm from ORIGINAL fp32 (exact reference values).
// ---------------------------------------------------------------------------
__global__ __launch_bounds__(256) void rownorm_kernel(
    const float* __restrict__ X, float* __restrict__ out, int nrows) {
  const int wave = threadIdx.x >> 6;
  const int lane = threadIdx.x & 63;
  const int row = blockIdx.x * 4 + wave;
  if (row >= nrows) return;
  const float* xr = X + (size_t)row * D_DIM;
  float4 a = *(const float4*)(xr + lane * 4);
  float4 b = *(const float4*)(xr + 256 + lane * 4);
  float s = a.x * a.x + a.y * a.y + a.z * a.z + a.w * a.w +
            b.x * b.x + b.y * b.y + b.z * b.z + b.w * b.w;
  #pragma unroll
  for (int o = 32; o > 0; o >>= 1) s += __shfl_xor(s, o, 64);
  if (lane == 0) out[row] = s;
}

// ---------------------------------------------------------------------------
// fp32 -> bf16 hi + bf16 residual (RNE). 8 floats per thread.
// ---------------------------------------------------------------------------
__device__ __forceinline__ unsigned bf_rne(float x) {
  unsigned u = __float_as_uint(x);
  return (u + 0x7fffu + ((u >> 16) & 1u)) >> 16;
}

__global__ __launch_bounds__(256) void cvt_kernel(
    const float* __restrict__ X, short* __restrict__ hi,
    short* __restrict__ lo, int n8) {
  const int i = blockIdx.x * 256 + threadIdx.x;
  if (i >= n8) return;
  const float4* p = (const float4*)(X + (size_t)i * 8);
  float4 x0 = p[0], x1 = p[1];
  float xs[8] = {x0.x, x0.y, x0.z, x0.w, x1.x, x1.y, x1.z, x1.w};
  union { short s[8]; int4 v; } H, L;
  #pragma unroll
  for (int j = 0; j < 8; ++j) {
    unsigned rh = bf_rne(xs[j]);
    H.s[j] = (short)rh;
    float h = __uint_as_float(rh << 16);
    L.s[j] = (short)bf_rne(xs[j] - h);
  }
  *(int4*)(hi + (size_t)i * 8) = H.v;
  *(int4*)(lo + (size_t)i * 8) = L.v;
}

// ---------------------------------------------------------------------------
// MFMA distance-argmin. Tile 128x128, BK=32 staged via global_load_lds into
// [kchunk][m][8 bf16] layout (contiguous 16-lane phases -> no bank conflicts).
// 4 waves, each 64x64 = 4x4 blocks of 16x16x32; 3 passes hi*hi + hi*lo + lo*hi.
// After the D loop: dist = (zz[r] + wsq[c]) - 2*dot, running per-lane argmin,
// tie-break lowest index. Split-K: each block scans KRANGE codes, emits one
// (val,idx) candidate per row.
// ---------------------------------------------------------------------------
__global__ __launch_bounds__(256, 2) void argmin_mfma_kernel(
    const short* __restrict__ zhi, const short* __restrict__ zlo,
    const short* __restrict__ whi, const short* __restrict__ wlo,
    const float* __restrict__ zz, const float* __restrict__ wsq,
    float* __restrict__ candv, int* __restrict__ candi) {
  __shared__ short Ah[4096], Al[4096], Bh[4096], Bl[4096];  // 8 KB each
  __shared__ float redv[BMT][32];
  __shared__ int   redi[BMT][32];

  const int tid = threadIdx.x;
  const int lane = tid & 63;
  const int wave = tid >> 6;
  const int wm = wave >> 1, wn = wave & 1;
  const int l15 = lane & 15, l4 = lane >> 4;

  const int bx = blockIdx.x;
  const int row0 = (bx >> 1) * BMT;
  const int k0 = (bx & 1) * KRANGE;

  // staging slots: slot s covers LDS bytes [s*16, s*16+16) = row (s&127),
  // k-chunk (s>>7) of the [4][128][8] tile; global row-major bf16 matches.
  const int r0s = tid & 127, kc0 = tid >> 7;
  const int slot1 = tid + 256;
  const int r1s = slot1 & 127, kc1 = slot1 >> 7;

  float zzr[16];
  #pragma unroll
  for (int rb = 0; rb < 4; ++rb)
    #pragma unroll
    for (int rg = 0; rg < 4; ++rg)
      zzr[rb * 4 + rg] = zz[row0 + wm * 64 + rb * 16 + l4 * 4 + rg];

  float best[16];
  int   bidx[16];
  #pragma unroll
  for (int i = 0; i < 16; ++i) { best[i] = INFINITY; bidx[i] = 0x7fffffff; }

  for (int kt = 0; kt < KRANGE; kt += BNT) {
    f32x4 acc[4][4];
    #pragma unroll
    for (int rb = 0; rb < 4; ++rb)
      #pragma unroll
      for (int cb = 0; cb < 4; ++cb) acc[rb][cb] = (f32x4)0.f;

    for (int d0 = 0; d0 < D_DIM; d0 += 32) {
      const size_t ga0 = (size_t)(row0 + r0s) * D_DIM + d0 + kc0 * 8;
      const size_t ga1 = (size_t)(row0 + r1s) * D_DIM + d0 + kc1 * 8;
      const size_t gb0 = (size_t)(k0 + kt + r0s) * D_DIM + d0 + kc0 * 8;
      const size_t gb1 = (size_t)(k0 + kt + r1s) * D_DIM + d0 + kc1 * 8;
      GLL16(zhi + ga0, Ah + (size_t)tid * 8);
      GLL16(zhi + ga1, Ah + (size_t)slot1 * 8);
      GLL16(zlo + ga0, Al + (size_t)tid * 8);
      GLL16(zlo + ga1, Al + (size_t)slot1 * 8);
      GLL16(whi + gb0, Bh + (size_t)tid * 8);
      GLL16(whi + gb1, Bh + (size_t)slot1 * 8);
      GLL16(wlo + gb0, Bl + (size_t)tid * 8);
      GLL16(wlo + gb1, Bl + (size_t)slot1 * 8);
      __syncthreads();  // drains vmcnt: DMA'd tiles visible

      bf16x8 ah[4], al[4], bh[4], bl[4];
      #pragma unroll
      for (int rb = 0; rb < 4; ++rb) {
        const int m = wm * 64 + rb * 16 + l15;
        ah[rb] = *(const bf16x8*)&Ah[(l4 * 128 + m) * 8];
        al[rb] = *(const bf16x8*)&Al[(l4 * 128 + m) * 8];
      }
      #pragma unroll
      for (int cb = 0; cb < 4; ++cb) {
        const int n = wn * 64 + cb * 16 + l15;
        bh[cb] = *(const bf16x8*)&Bh[(l4 * 128 + n) * 8];
        bl[cb] = *(const bf16x8*)&Bl[(l4 * 128 + n) * 8];
      }
      #pragma unroll
      for (int rb = 0; rb < 4; ++rb)
        #pragma unroll
        for (int cb = 0; cb < 4; ++cb) {
          acc[rb][cb] = __builtin_amdgcn_mfma_f32_16x16x32_bf16(
              ah[rb], bh[cb], acc[rb][cb], 0, 0, 0);
          acc[rb][cb] = __builtin_amdgcn_mfma_f32_16x16x32_bf16(
              ah[rb], bl[cb], acc[rb][cb], 0, 0, 0);
          acc[rb][cb] = __builtin_amdgcn_mfma_f32_16x16x32_bf16(
              al[rb], bh[cb], acc[rb][cb], 0, 0, 0);
        }
      __syncthreads();  // all frag reads done before next chunk's DMA
    }

    // score this 128-code tile; C/D layout: col=lane&15, row=(lane>>4)*4+reg
    #pragma unroll
    for (int cb = 0; cb < 4; ++cb) {
      const int col = k0 + kt + wn * 64 + cb * 16 + l15;
      const float wv = wsq[col];
      #pragma unroll
      for (int rb = 0; rb < 4; ++rb) {
        f32x4 a = acc[rb][cb];
        #pragma unroll
        for (int rg = 0; rg < 4; ++rg) {
          const float dist = (zzr[rb * 4 + rg] + wv) - 2.0f * a[rg];
          const int s = rb * 4 + rg;
          if (dist < best[s]) { best[s] = dist; bidx[s] = col; }
        }
      }
    }
  }

  // cross-lane reduction: 32 candidates per row (16 lanes x 2 wn-waves)
  #pragma unroll
  for (int rb = 0; rb < 4; ++rb)
    #pragma unroll
    for (int rg = 0; rg < 4; ++rg) {
      const int R = wm * 64 + rb * 16 + l4 * 4 + rg;
      redv[R][wn * 16 + l15] = best[rb * 4 + rg];
      redi[R][wn * 16 + l15] = bidx[rb * 4 + rg];
    }
  __syncthreads();

  if (tid < BMT) {
    float bv = INFINITY;
    int bi = 0x7fffffff;
    #pragma unroll
    for (int t = 0; t < 32; ++t) {
      const float v = redv[tid][t];
      const int ix = redi[tid][t];
      if (v < bv || (v == bv && ix < bi)) { bv = v; bi = ix; }
    }
    candv[(size_t)(bx & 1) * B_ROWS + row0 + tid] = bv;
    candi[(size_t)(bx & 1) * B_ROWS + row0 + tid] = bi;
  }
}

// ---------------------------------------------------------------------------
// Merge split-K candidates, write indices (int + float), histogram.
// ---------------------------------------------------------------------------
__global__ __launch_bounds__(256) void merge_kernel(
    const float* __restrict__ candv, const int* __restrict__ candi,
    int* __restrict__ out_idx, float* __restrict__ out_idx_f,
    int* __restrict__ hist) {
  const int row = blockIdx.x * 256 + threadIdx.x;
  const float v0 = candv[row];
  const int i0 = candi[row];
  const float v1 = candv[B_ROWS + row];
  const int i1 = candi[B_ROWS + row];
  int bi = (v1 < v0 || (v1 == v0 && i1 < i0)) ? i1 : i0;
  out_idx[row] = bi;
  out_idx_f[row] = (float)bi;
  atomicAdd(&hist[bi], 1);
}

// ---------------------------------------------------------------------------
// Gather W[idx], straight-through output, MSE accumulation.
// ---------------------------------------------------------------------------
__global__ __launch_bounds__(256) void gather_kernel(
    const float* __restrict__ z, const float* __restrict__ W,
    const int* __restrict__ idx, float* __restrict__ out,
    double* __restrict__ mse_sum) {
  const int wave = threadIdx.x >> 6;
  const int lane = threadIdx.x & 63;
  const int row = blockIdx.x * 4 + wave;
  const int k = idx[row];
  const float* zr = z + (size_t)row * D_DIM;
  const float* wr = W + (size_t)k * D_DIM;
  float* outr = out + (size_t)row * D_DIM;
  float s = 0.f;
  #pragma unroll
  for (int h = 0; h < 2; ++h) {
    const int c = h * 256 + lane * 4;
    float4 zv = *(const float4*)(zr + c);
    float4 qv = *(const float4*)(wr + c);
    float4 st;
    st.x = zv.x + (qv.x - zv.x);
    st.y = zv.y + (qv.y - zv.y);
    st.z = zv.z + (qv.z - zv.z);
    st.w = zv.w + (qv.w - zv.w);
    float dx = zv.x - qv.x, dy = zv.y - qv.y, dz = zv.z - qv.z, dw = zv.w - qv.w;
    s += dx * dx + dy * dy + dz * dz + dw * dw;
    *(float4*)(outr + c) = st;
  }
  #pragma unroll
  for (int o = 32; o > 0; o >>= 1) s += __shfl_xor(s, o, 64);
  if (lane == 0) atomicAdd(mse_sum, (double)s);
}

// ---------------------------------------------------------------------------
__global__ __launch_bounds__(256) void loss_kernel(
    const int* __restrict__ hist, const double* __restrict__ mse_sum,
    float* __restrict__ out_loss) {
  __shared__ float ls[4];
  const int tid = threadIdx.x;
  float e = 0.f;
  for (int b = tid; b < K_EMB; b += 256) {
    float p = (float)hist[b] * (1.0f / 32768.0f);
    e += p * logf(p + 1e-10f);
  }
  #pragma unroll
  for (int o = 32; o > 0; o >>= 1) e += __shfl_xor(e, o, 64);
  if ((tid & 63) == 0) ls[tid >> 6] = e;
  __syncthreads();
  if (tid == 0) {
    float entropy = -(ls[0] + ls[1] + ls[2] + ls[3]);
    float mse = (float)(*mse_sum / 16777216.0);
    float entropy_loss = 1.0f - entropy / logf(8192.0f);
    out_loss[0] = mse + 0.25f * mse + 0.1f * entropy_loss;
  }
}

// ---------------------------------------------------------------------------
extern "C" void kernel_launch(void* const* d_in, const int* in_sizes, int n_in,
                              void* d_out, int out_size, void* d_ws, size_t ws_size,
                              hipStream_t stream) {
  const float* z = (const float*)d_in[0];  // [32768,512]
  const float* W = (const float*)d_in[1];  // [8192,512]
  float* out = (float*)d_out;              // [B*D] st | [1] loss | [B] indices

  char* ws = (char*)d_ws;
  double* mse_sum = (double*)ws;                 // @0
  int*   hist  = (int*)  (ws + 256);             // 32 KB
  float* zz    = (float*)(ws + 33024);           // 128 KB
  float* wsq   = (float*)(ws + 164096);          // 32 KB
  int*   idx   = (int*)  (ws + 196864);          // 128 KB
  float* candv = (float*)(ws + 327936);          // 256 KB
  int*   candi = (int*)  (ws + 590080);          // 256 KB
  short* zhi   = (short*)(ws + 1048576);         // 32 MB
  short* zlo   = (short*)(ws + 1048576 + 33554432);
  short* whi   = (short*)(ws + 1048576 + 2 * 33554432);
  short* wlo   = (short*)(ws + 1048576 + 2 * 33554432 + 8388608);

  hipMemsetAsync(d_ws, 0, 33024, stream);  // mse_sum + hist

  cvt_kernel<<<(B_ROWS * D_DIM / 8 + 255) / 256, 256, 0, stream>>>(
      z, zhi, zlo, B_ROWS * D_DIM / 8);
  cvt_kernel<<<(K_EMB * D_DIM / 8 + 255) / 256, 256, 0, stream>>>(
      W, whi, wlo, K_EMB * D_DIM / 8);

  rownorm_kernel<<<B_ROWS / 4, 256, 0, stream>>>(z, zz, B_ROWS);
  rownorm_kernel<<<K_EMB / 4, 256, 0, stream>>>(W, wsq, K_EMB);

  argmin_mfma_kernel<<<(B_ROWS / BMT) * KSPLIT, 256, 0, stream>>>(
      zhi, zlo, whi, wlo, zz, wsq, candv, candi);

  merge_kernel<<<B_ROWS / 256, 256, 0, stream>>>(
      candv, candi, idx, out + (size_t)B_ROWS * D_DIM + 1, hist);

  gather_kernel<<<B_ROWS / 4, 256, 0, stream>>>(z, W, idx, out, mse_sum);

  loss_kernel<<<1, 256, 0, stream>>>(hist, mse_sum,
                                     out + (size_t)B_ROWS * D_DIM);
}